// Round 1
// baseline (252.006 us; speedup 1.0000x reference)
//
#include <hip/hip_runtime.h>

// Magnus 4th-order step, B=65536 batches of N=16 systems.
//
// Math: alpha1 = h/2*(A1+A2); alpha2 = h*sqrt(3)*(A2-A1)
//       Omega  = alpha1 - (alpha1@alpha2 - alpha2@alpha1)/12
//       y_next = expm(Omega) @ y0;  aux = stack(A1, A2)
//
// ||Omega||_1 ~ 0.03 worst-case, so expm(Omega)@y0 via 5-term Taylor
// (error <= ||Omega||^6/720 ~ 1e-12) needs no Pade / scaling-squaring,
// and we never materialize U: Omega*v = a1*v - (a1*(a2*v) - a2*(a1*v))/12
// is 4 matvecs. 16 lanes per batch element; lane r holds row r of
// alpha1/alpha2 in registers; matvec broadcast via __shfl(width=16).
// The aux copy is fused so A1/A2 are read from HBM exactly once.

static constexpr int kB = 65536;
static constexpr int kN = 16;

__global__ __launch_bounds__(256) void magnus4_kernel(
    const float* __restrict__ A1,
    const float* __restrict__ A2,
    const float* __restrict__ y0,
    const float* __restrict__ hp,
    float* __restrict__ out)
{
    const int t = blockIdx.x * 256 + threadIdx.x;
    const int b = t >> 4;          // batch index
    const int r = t & 15;          // row index within the 16x16 matrix
    const int base = (b << 8) + (r << 4);   // element offset of row r of batch b

    // ---- load row r of A1 and A2 (4x float4 each, 64B-aligned) ----
    const float4* __restrict__ a1p = reinterpret_cast<const float4*>(A1 + base);
    const float4* __restrict__ a2p = reinterpret_cast<const float4*>(A2 + base);
    float4 a1[4], a2[4];
#pragma unroll
    for (int c = 0; c < 4; ++c) a1[c] = a1p[c];
#pragma unroll
    for (int c = 0; c < 4; ++c) a2[c] = a2p[c];

    // ---- fused aux writeback: out layout = [y_next (B*N)] [A1 (B*N*N)] [A2 (B*N*N)] ----
    float4* __restrict__ o1 = reinterpret_cast<float4*>(out + (kB * kN) + base);
    float4* __restrict__ o2 = reinterpret_cast<float4*>(out + (kB * kN) + (kB * kN * kN) + base);
#pragma unroll
    for (int c = 0; c < 4; ++c) o1[c] = a1[c];
#pragma unroll
    for (int c = 0; c < 4; ++c) o2[c] = a2[c];

    // ---- build alpha1/alpha2 rows in registers ----
    const float h  = *hp;
    const float c1 = 0.5f * h;
    const float c2 = 1.73205080756887729f * h;   // h*sqrt(3)

    float w1[16], w2[16];
#pragma unroll
    for (int c = 0; c < 4; ++c) {
        const float4 x1 = a1[c], x2 = a2[c];
        w1[4*c+0] = c1 * (x1.x + x2.x);  w2[4*c+0] = c2 * (x2.x - x1.x);
        w1[4*c+1] = c1 * (x1.y + x2.y);  w2[4*c+1] = c2 * (x2.y - x1.y);
        w1[4*c+2] = c1 * (x1.z + x2.z);  w2[4*c+2] = c2 * (x2.z - x1.z);
        w1[4*c+3] = c1 * (x1.w + x2.w);  w2[4*c+3] = c2 * (x2.w - x1.w);
    }

    // ---- Taylor: y = sum_{k=0..5} Omega^k y0 / k! ----
    const float v0 = y0[(b << 4) + r];
    float y = v0;
    float term = v0;
#pragma unroll
    for (int k = 1; k <= 5; ++k) {
        // stage 1: u1 = alpha1*term, u2 = alpha2*term (shared broadcasts)
        float u1a = 0.f, u1b = 0.f, u2a = 0.f, u2b = 0.f;
#pragma unroll
        for (int j = 0; j < 16; j += 2) {
            const float t0 = __shfl(term, j, 16);
            const float t1 = __shfl(term, j + 1, 16);
            u1a = fmaf(w1[j],   t0, u1a);
            u2a = fmaf(w2[j],   t0, u2a);
            u1b = fmaf(w1[j+1], t1, u1b);
            u2b = fmaf(w2[j+1], t1, u2b);
        }
        const float u1 = u1a + u1b;
        const float u2 = u2a + u2b;
        // stage 2: s1 = alpha1*u2, s2 = alpha2*u1
        float s1a = 0.f, s1b = 0.f, s2a = 0.f, s2b = 0.f;
#pragma unroll
        for (int j = 0; j < 16; j += 2) {
            const float p0 = __shfl(u2, j, 16);
            const float q0 = __shfl(u1, j, 16);
            const float p1 = __shfl(u2, j + 1, 16);
            const float q1 = __shfl(u1, j + 1, 16);
            s1a = fmaf(w1[j],   p0, s1a);
            s2a = fmaf(w2[j],   q0, s2a);
            s1b = fmaf(w1[j+1], p1, s1b);
            s2b = fmaf(w2[j+1], q1, s2b);
        }
        const float s1 = s1a + s1b;
        const float s2 = s2a + s2b;
        // Omega*term = u1 - (s1 - s2)/12 ; then term /= k for the factorial
        const float om = u1 - (s1 - s2) * (1.0f / 12.0f);
        term = om * (1.0f / (float)k);
        y += term;
    }

    out[(b << 4) + r] = y;
}

extern "C" void kernel_launch(void* const* d_in, const int* in_sizes, int n_in,
                              void* d_out, int out_size, void* d_ws, size_t ws_size,
                              hipStream_t stream) {
    const float* A1 = (const float*)d_in[0];
    const float* A2 = (const float*)d_in[1];
    const float* y0 = (const float*)d_in[2];
    const float* hp = (const float*)d_in[3];
    float* out = (float*)d_out;

    const int threads = kB * kN;             // 1,048,576 threads, 16 per batch elem
    magnus4_kernel<<<threads / 256, 256, 0, stream>>>(A1, A2, y0, hp, out);
}